// Round 1
// baseline (502.815 us; speedup 1.0000x reference)
//
#include <hip/hip_runtime.h>
#include <math.h>

// Problem geometry (fixed by reference):
//   in1: (8,256, 64, 64)  pool k=2  -> p1 (8,256,32,32)
//   in2: (8,128,128,128)  pool k=4  -> p2 (8,128,32,32)
//   in3: (8, 64,256,256)  pool k=8  -> p3 (8, 64,32,32)
//   in4: (8, 32,512,512)  pool k=16 -> p4 (8, 32,32,32)
//   out[b,c,h,w] = relu(p1[b,c%256,h,w] + p2[b,c%128,h,w] + p3[b,c%64,h,w]
//                       + p4[b,c%32,h,w] + ff[b,c,h,w])
//
// Workspace layout (floats):
//   p1 @ 0         (2,097,152)
//   p2 @ 2,097,152 (1,048,576)
//   p3 @ 3,145,728 (  524,288)
//   p4 @ 3,670,016 (  262,144)   total 15.0 MiB

#define P1_OFF 0
#define P2_OFF 2097152
#define P3_OFF 3145728
#define P4_OFF 3670016

__device__ __forceinline__ float max4(float4 v) {
    return fmaxf(fmaxf(v.x, v.y), fmaxf(v.z, v.w));
}

template <int K>
__device__ __forceinline__ float pool_window(const float* __restrict__ p, int W) {
    float m = -INFINITY;
#pragma unroll
    for (int r = 0; r < K; ++r) {
        const float* row = p + r * W;
        if (K == 2) {
            float2 v = *(const float2*)row;
            m = fmaxf(m, fmaxf(v.x, v.y));
        } else {
#pragma unroll
            for (int c = 0; c < K; c += 4) {
                float4 v = *(const float4*)(row + c);
                m = fmaxf(m, max4(v));
            }
        }
    }
    return m;
}

// Block ranges (256 threads each, 1 thread = 1 pooled output pixel):
//   in4 (k=16): blocks [    0,  1024)   262,144 px  <- heaviest first
//   in3 (k= 8): blocks [ 1024,  3072)   524,288 px
//   in2 (k= 4): blocks [ 3072,  7168) 1,048,576 px
//   in1 (k= 2): blocks [ 7168, 15360) 2,097,152 px
__global__ __launch_bounds__(256) void pool_all_kernel(
    const float* __restrict__ in1, const float* __restrict__ in2,
    const float* __restrict__ in3, const float* __restrict__ in4,
    float* __restrict__ ws) {
    const int blk = blockIdx.x;
    const int tid = threadIdx.x;

    if (blk < 1024) {                       // in4, k=16, W=H=512
        const int opix = blk * 256 + tid;
        const int ow = opix & 31, oh = (opix >> 5) & 31, bc = opix >> 10;
        const float* p = in4 + bc * (512 * 512) + (oh * 16) * 512 + ow * 16;
        ws[P4_OFF + opix] = pool_window<16>(p, 512);
    } else if (blk < 3072) {                // in3, k=8, W=H=256
        const int opix = (blk - 1024) * 256 + tid;
        const int ow = opix & 31, oh = (opix >> 5) & 31, bc = opix >> 10;
        const float* p = in3 + bc * (256 * 256) + (oh * 8) * 256 + ow * 8;
        ws[P3_OFF + opix] = pool_window<8>(p, 256);
    } else if (blk < 7168) {                // in2, k=4, W=H=128
        const int opix = (blk - 3072) * 256 + tid;
        const int ow = opix & 31, oh = (opix >> 5) & 31, bc = opix >> 10;
        const float* p = in2 + bc * (128 * 128) + (oh * 4) * 128 + ow * 4;
        ws[P2_OFF + opix] = pool_window<4>(p, 128);
    } else {                                // in1, k=2, W=H=64
        const int opix = (blk - 7168) * 256 + tid;
        const int ow = opix & 31, oh = (opix >> 5) & 31, bc = opix >> 10;
        const float* p = in1 + bc * (64 * 64) + (oh * 2) * 64 + ow * 2;
        ws[P1_OFF + opix] = pool_window<2>(p, 64);
    }
}

// One thread = one float4 of the output. 8*512*32*32/4 = 1,048,576 threads.
__global__ __launch_bounds__(256) void combine_kernel(
    const float* __restrict__ ff, const float* __restrict__ ws,
    float* __restrict__ out) {
    const int t = blockIdx.x * 256 + threadIdx.x;   // float4 index
    const int b = t >> 17;          // 512*256 float4 per image
    const int r = t & 131071;
    const int c = r >> 8;           // channel 0..511
    const int q = r & 255;          // float4 within 32x32 plane

    const float4* ff4 = (const float4*)ff;
    const float4* p1 = (const float4*)(ws + P1_OFF);
    const float4* p2 = (const float4*)(ws + P2_OFF);
    const float4* p3 = (const float4*)(ws + P3_OFF);
    const float4* p4 = (const float4*)(ws + P4_OFF);

    float4 a  = ff4[t];
    float4 v1 = p1[(b * 256 + (c & 255)) * 256 + q];
    float4 v2 = p2[(b * 128 + (c & 127)) * 256 + q];
    float4 v3 = p3[(b *  64 + (c &  63)) * 256 + q];
    float4 v4 = p4[(b *  32 + (c &  31)) * 256 + q];

    float4 o;
    o.x = fmaxf(a.x + v1.x + v2.x + v3.x + v4.x, 0.0f);
    o.y = fmaxf(a.y + v1.y + v2.y + v3.y + v4.y, 0.0f);
    o.z = fmaxf(a.z + v1.z + v2.z + v3.z + v4.z, 0.0f);
    o.w = fmaxf(a.w + v1.w + v2.w + v3.w + v4.w, 0.0f);
    ((float4*)out)[t] = o;
}

extern "C" void kernel_launch(void* const* d_in, const int* in_sizes, int n_in,
                              void* d_out, int out_size, void* d_ws, size_t ws_size,
                              hipStream_t stream) {
    const float* in1 = (const float*)d_in[0];
    const float* in2 = (const float*)d_in[1];
    const float* in3 = (const float*)d_in[2];
    const float* in4 = (const float*)d_in[3];
    const float* ff  = (const float*)d_in[4];
    float* ws  = (float*)d_ws;
    float* out = (float*)d_out;

    pool_all_kernel<<<15360, 256, 0, stream>>>(in1, in2, in3, in4, ws);
    combine_kernel<<<4096, 256, 0, stream>>>(ff, ws, out);
}